// Round 7
// baseline (511.147 us; speedup 1.0000x reference)
//
#include <hip/hip_runtime.h>
#include <math.h>

#define K_POLY   20000
#define PMAX     30
#define NUM_PTS  5
#define C_MID    112
#define C_OUT    224
#define PE_DIM   32
#define GEO_DIM  256
#define M_ROWS   (K_POLY*NUM_PTS)        // 100000

#define NTILES   14                      // 224/16 n-tiles
#define KSTEPS   11                      // K padded 336 -> 352 = 11*32
#define WP_ELEMS (KSTEPS*NTILES*64*8)    // 78848 bf16 = 157696 B
#define NPACK_BLK ((WP_ELEMS+255)/256)   // 308

// A stored in MFMA-fragment order by 16-row group:
//   elem (r,k) -> ushort addr g*GROUP_US + (k>>5)*512 + lane*8 + (k&7),
//   lane = ((k>>3)&3)*16 + (r&15), g = r>>4.
#define GROUP_US 8192                    // ushorts per 16-row group region

#define ROWS_W   32                      // rows per prep unit; 100000 = 3125*32
#define NUNITS   (M_ROWS/ROWS_W)         // 3125
#define NPREP_BLK NUNITS                 // one 256-thread prep block per unit

#define NGROUPS  (M_ROWS/16)             // 6250 16-row groups
#define WAVES2_B 16                      // 1024-thread gemm2 blocks (4 waves/SIMD)
#define NBLK2    256                     // 1 block/CU (LDS-bound)
#define TOTW2    (NBLK2*WAVES2_B)        // 4096 waves; 2154 do a 2nd group

typedef __attribute__((ext_vector_type(8))) short short8;
typedef __attribute__((ext_vector_type(4))) float f32x4;

__device__ inline unsigned short f2bf(float f) {
    union { float f; unsigned u; } v; v.f = f;
    return (unsigned short)((v.u + 0x7fffu + ((v.u >> 16) & 1u)) >> 16);
}

#define GLDS(gp, lp) __builtin_amdgcn_global_load_lds( \
    (const __attribute__((address_space(1))) void*)(gp), \
    (__attribute__((address_space(3))) void*)(lp), 16, 0, 0)

#define SH_PITCH 120   // ushort pitch of s_h rows (2-way banks max)

// ---- kernel 1: w2 pack (blocks [0,308)) + per-unit poly prep (rest) ----
__global__ __launch_bounds__(256) void prep_pack(
    const float* __restrict__ geoms, const int* __restrict__ lengths,
    const float* __restrict__ w1, const float* __restrict__ b1,
    const float* __restrict__ w2,
    const int* __restrict__ roi_w, const int* __restrict__ roi_h,
    unsigned short* __restrict__ Wp, float* __restrict__ out)
{
    __shared__ unsigned short s_h[40 * SH_PITCH];   // 9600 B: conv1 bf16, row-local

    if (blockIdx.x < NPACK_BLK) {
        int i = blockIdx.x * 256 + threadIdx.x;
        if (i < WP_ELEMS) {
            int j    = i & 7;
            int lane = (i >> 3) & 63;
            int grp  = i >> 9;               // ks*14 + nt
            int nt   = grp % NTILES;
            int ks   = grp / NTILES;
            int k    = ks * 32 + (lane >> 4) * 8 + j;   // k = dk*112 + c
            int n    = nt * 16 + (lane & 15);
            float v = 0.f;
            if (k < 336) {
                int dk = k / C_MID, c = k - dk * C_MID;
                v = w2[(n * C_MID + c) * 3 + dk];
            }
            Wp[i] = f2bf(v);
        }
        return;
    }

    const int ub     = blockIdx.x - NPACK_BLK;       // 0..3124
    const int rbase0 = ub * ROWS_W;
    const int pstart = rbase0 / 5;
    const int npoly  = (rbase0 + 31) / 5 - pstart + 1;   // 7 or 8

    const int t = threadIdx.x, lane = t & 63, wave = t >> 6;
    const float roiw  = (float)roi_w[0], roih = (float)roi_h[0];
    const float halfx = roiw * 0.5f, halfy = roih * 0.5f;

    // ---- per-wave: resample + conv1 for polys pstart+lp (lp = wave, wave+4) ----
    for (int lp = wave; lp < 8; lp += 4) {
        if (lp < npoly) {
            const int poly = pstart + lp;
            const float* gp = geoms + (size_t)poly * (PMAX * 2);
            float px = 0.f, py = 0.f;
            if (lane < PMAX) { float2 p = ((const float2*)gp)[lane]; px = p.x; py = p.y; }
            const int L = lengths[poly];

            float nx = __shfl(px, lane + 1);
            float ny = __shfl(py, lane + 1);
            float seg = 0.f;
            if (lane < L - 1 && lane < PMAX - 1) {
                float dx = nx - px, dy = ny - py;
                float sq = dx * dx + dy * dy;
                seg = (sq > 0.f) ? sqrtf(sq) : 0.f;
            }
            float incl = seg;
            #pragma unroll
            for (int d = 1; d < 32; d <<= 1) {
                float v = __shfl_up(incl, d, 32);
                if ((lane & 31) >= d) incl += v;
            }
            float cum = __shfl_up(incl, 1, 32);
            if ((lane & 31) == 0) cum = 0.f;
            const float total = __shfl(incl, PMAX - 2);
            const bool degen = total < 1e-6f;
            const float x0g = __shfl(px, 0), y0g = __shfl(py, 0);

            float bxv[NUM_PTS], byv[NUM_PTS];
            #pragma unroll
            for (int j = 0; j < NUM_PTS; ++j) {
                float tj = total * (0.25f * (float)j);
                unsigned long long mlt = __ballot(lane < PMAX && cum < tj);
                int idx = (int)__popcll(mlt);
                idx = max(1, min(idx, L - 1));
                float c1 = __shfl(cum, idx - 1);
                float s1 = __shfl(seg, idx - 1);
                float ax = __shfl(px, idx - 1), ay = __shfl(py, idx - 1);
                float bx2 = __shfl(px, idx),    by2 = __shfl(py, idx);
                float tt = (tj - c1) / (s1 + 1e-8f);
                float fx = degen ? x0g : ax + tt * (bx2 - ax);
                float fy = degen ? y0g : ay + tt * (by2 - ay);
                bxv[j] = (fx + halfx) / roiw;
                byv[j] = (fy + halfy) / roih;
            }
            if (lane == 0) {
                float* co = out + (size_t)M_ROWS * GEO_DIM + (size_t)poly * (NUM_PTS * 2);
                #pragma unroll
                for (int j = 0; j < NUM_PTS; ++j) { co[2 * j] = bxv[j]; co[2 * j + 1] = byv[j]; }
            }

            // conv1 (2->112) + ReLU -> bf16 in s_h (one channel per lane)
            #pragma unroll
            for (int it = 0; it < 2; ++it) {
                int c = it * 64 + lane;
                if (c < C_MID) {
                    const float* w = w1 + c * 6;
                    float w0 = w[0], wa = w[1], wb = w[2], w3 = w[3], w4 = w[4], w5 = w[5];
                    float bb = b1[c];
                    #pragma unroll
                    for (int pp = 0; pp < NUM_PTS; ++pp) {
                        float acc = bb + bxv[pp] * wa + byv[pp] * w4;
                        if (pp > 0)           acc += bxv[pp - 1] * w0 + byv[pp - 1] * w3;
                        if (pp < NUM_PTS - 1) acc += bxv[pp + 1] * wb + byv[pp + 1] * w5;
                        s_h[(lp * 5 + pp) * SH_PITCH + c] = f2bf(fmaxf(acc, 0.f));
                    }
                }
            }
        }
    }
    __syncthreads();

    // ---- cooperative coalesced A-frag write: 2 groups x 11 ks x 64 lanes ----
    unsigned short* Af = (unsigned short*)out;
    for (int cidx = t; cidx < 2 * KSTEPS * 64; cidx += 256) {
        int gl  = cidx / (KSTEPS * 64);
        int rem = cidx - gl * (KSTEPS * 64);
        int ks  = rem >> 6;
        int ln  = rem & 63;
        int q   = ln >> 4, rr = ln & 15;
        int r   = (2 * ub + gl) * 16 + rr;       // global row, always < M_ROWS
        int p   = r % 5;
        int lp5 = (r - pstart * 5) - p;          // lp*5

        union { short8 v; unsigned long long u2[2]; } val;
        val.u2[0] = 0ull; val.u2[1] = 0ull;
        int k0 = ks * 32 + q * 8;
        if (k0 < 336) {
            int dk = k0 / C_MID;
            int c0 = k0 - dk * C_MID;            // multiple of 8 within dk
            int pp = p + dk - 1;
            if (pp >= 0 && pp < NUM_PTS)
                val.v = *(const short8*)&s_h[(lp5 + pp) * SH_PITCH + c0];
        }
        *(short8*)(Af + (size_t)(2 * ub + gl) * GROUP_US + ks * 512 + ln * 8) = val.v;
    }
}

// ---- kernel 2: all-B-in-LDS MFMA conv2, 16 waves/block (4/SIMD), 16-row groups ----
__global__ __launch_bounds__(1024, 4) void gemm2(
    const unsigned short* __restrict__ Wp,
    const float* __restrict__ b2, const float* __restrict__ gamma,
    const float* __restrict__ beta, float* __restrict__ out)
{
    __shared__ __align__(16) unsigned short s_B[WP_ELEMS];   // 157696 B

    const int t = threadIdx.x, lane = t & 63, wave = t >> 6;
    const int quad = lane >> 4, m = lane & 15;

    // ---- stage ALL of Wp into LDS (9856 x 16B chunks over 1024 threads) ----
    #pragma unroll
    for (int it = 0; it < 10; ++it) {
        int idx = t + it * 1024;
        if (idx < WP_ELEMS / 8)
            GLDS((const char*)Wp + (size_t)idx * 16, (char*)s_B + idx * 16);
    }
    __syncthreads();

    const unsigned short* Af = (const unsigned short*)out;
    const float* cptr = out + (size_t)M_ROWS * GEO_DIM;
    const unsigned short* bl = s_B + lane * 8;   // per-lane B base; frag stride 512

    for (int g = blockIdx.x * WAVES2_B + wave; g < NGROUPS; g += TOTW2) {
        const int rw = g * 16;

        // A frag base: group g (rows rw..rw+15), contiguous 1KB per ks
        const unsigned short* Ab0 = Af + (size_t)g * GROUP_US + lane * 8;

        // coords for the group's 16 rows: one coalesced 32-float load, shfl later
        float cv = (lane < 32) ? cptr[(size_t)rw * 2 + lane] : 0.f;

        f32x4 acc[NTILES];
        #pragma unroll
        for (int nt = 0; nt < NTILES; ++nt)
            #pragma unroll
            for (int i = 0; i < 4; ++i) acc[nt][i] = 0.f;

        short8 a0 = *(const short8*)Ab0;
        #pragma unroll
        for (int ks = 0; ks < KSTEPS; ++ks) {
            short8 a0n = a0;
            if (ks < KSTEPS - 1)
                a0n = *(const short8*)(Ab0 + (ks + 1) * 512);
            const unsigned short* bp = bl + ks * (NTILES * 512);
            __builtin_amdgcn_s_setprio(1);
            #pragma unroll
            for (int nt = 0; nt < NTILES; ++nt) {
                short8 b = *(const short8*)(bp + nt * 512);
                acc[nt] = __builtin_amdgcn_mfma_f32_16x16x32_bf16(a0, b, acc[nt], 0, 0, 0);
            }
            __builtin_amdgcn_s_setprio(0);
            a0 = a0n;
        }

        // ---- PE: cols 0..31 for rows rw..rw+15 (coords via shfl of cv) ----
        {
            const int col = lane & 31;
            const int d = col >> 4, isc = (col >> 3) & 1, fr = col & 7;
            const float pef = (float)(1 << fr) * 3.14159265358979323846f;
            #pragma unroll
            for (int it = 0; it < 8; ++it) {
                int j2 = it * 2 + (lane >> 5);          // row offset 0..15
                float x = __shfl(cv, j2 * 2 + d);
                float arg = x * pef;
                out[(size_t)(rw + j2) * GEO_DIM + col] = isc ? __cosf(arg) : __sinf(arg);
            }
        }

        // ---- bias + ReLU + in-wave LayerNorm + store cols 32..255 ----
        // (loaded after the MFMA loop so they don't inflate MFMA-phase pressure)
        float bias[NTILES], gm[NTILES], bt[NTILES];
        #pragma unroll
        for (int nt = 0; nt < NTILES; ++nt) {
            int col = nt * 16 + m;
            bias[nt] = b2[col]; gm[nt] = gamma[col]; bt[nt] = beta[col];
        }

        #pragma unroll
        for (int i = 0; i < 4; ++i) {
            float s = 0.f, q = 0.f;
            #pragma unroll
            for (int nt = 0; nt < NTILES; ++nt) {
                float v = fmaxf(acc[nt][i] + bias[nt], 0.f);
                acc[nt][i] = v;
                s += v; q += v * v;
            }
            #pragma unroll
            for (int mk = 8; mk >= 1; mk >>= 1) {
                s += __shfl_xor(s, mk, 64);
                q += __shfl_xor(q, mk, 64);
            }
            float mu  = s * (1.f / C_OUT);
            float var = fmaxf(q * (1.f / C_OUT) - mu * mu, 0.f);
            float rs  = rsqrtf(var + 1e-5f);
            int r = rw + quad * 4 + i;               // always < M_ROWS
            size_t ob = (size_t)r * GEO_DIM + PE_DIM + m;
            #pragma unroll
            for (int nt = 0; nt < NTILES; ++nt)
                out[ob + nt * 16] = (acc[nt][i] - mu) * rs * gm[nt] + bt[nt];
        }
    }
}

extern "C" void kernel_launch(void* const* d_in, const int* in_sizes, int n_in,
                              void* d_out, int out_size, void* d_ws, size_t ws_size,
                              hipStream_t stream) {
    const float* geoms   = (const float*)d_in[0];
    const int*   lengths = (const int*)d_in[1];
    const float* w1      = (const float*)d_in[2];
    const float* b1      = (const float*)d_in[3];
    const float* w2      = (const float*)d_in[4];
    const float* b2      = (const float*)d_in[5];
    const float* gamma   = (const float*)d_in[6];
    const float* beta    = (const float*)d_in[7];
    const int*   roi_w   = (const int*)d_in[8];
    const int*   roi_h   = (const int*)d_in[9];
    float* out = (float*)d_out;
    unsigned short* Wp = (unsigned short*)d_ws;   // 157696 B

    hipLaunchKernelGGL(prep_pack, dim3(NPACK_BLK + NPREP_BLK), dim3(256), 0, stream,
                       geoms, lengths, w1, b1, w2, roi_w, roi_h, Wp, out);
    hipLaunchKernelGGL(gemm2, dim3(NBLK2), dim3(1024), 0, stream, Wp, b2, gamma, beta, out);
}

// Round 8
// 221.114 us; speedup vs baseline: 2.3117x; 2.3117x over previous
//
#include <hip/hip_runtime.h>
#include <math.h>

#define K_POLY   20000
#define PMAX     30
#define NUM_PTS  5
#define C_MID    112
#define C_OUT    224
#define PE_DIM   32
#define GEO_DIM  256
#define M_ROWS   (K_POLY*NUM_PTS)        // 100000

#define NTILES   14                      // 224/16 n-tiles
#define KSTEPS   11                      // K padded 336 -> 352 = 11*32
#define WP_ELEMS (KSTEPS*NTILES*64*8)    // 78848 bf16 = 157696 B
#define NPACK_BLK ((WP_ELEMS+255)/256)   // 308
#define POLY_PER_BLK 4
#define NPREP_BLK ((K_POLY+POLY_PER_BLK-1)/POLY_PER_BLK)  // 5000

// in-place A storage: per-poly chunk of 7*112 bf16 (+16 pad) living in the
// cols-32..255 region of that poly's 5 output rows (overwritten later by LN)
#define CHUNK_STRIDE 2560    // ushort elems per poly block (5 rows * 256 * 2)
#define CHUNK_OFF    64      // ushort offset of chunk start (row 0, col 32)

#define ROWS_W   30                      // rows per wave-unit (6 whole polys)
#define NUNITS   ((M_ROWS+ROWS_W-1)/ROWS_W)     // 3334
#define WAVES2_B 12                      // 768-thread gemm2 blocks (3 waves/SIMD)
#define NBLK2    256                     // 1 block/CU (LDS-bound)
#define TOTW2    (NBLK2*WAVES2_B)        // 3072 waves; 262 do a 2nd unit

typedef __attribute__((ext_vector_type(8))) short short8;
typedef __attribute__((ext_vector_type(4))) float f32x4;

__device__ inline unsigned short f2bf(float f) {
    union { float f; unsigned u; } v; v.f = f;
    return (unsigned short)((v.u + 0x7fffu + ((v.u >> 16) & 1u)) >> 16);
}

#define GLDS(gp, lp) __builtin_amdgcn_global_load_lds( \
    (const __attribute__((address_space(1))) void*)(gp), \
    (__attribute__((address_space(3))) void*)(lp), 16, 0, 0)

// ---- kernel 1: w2 pack (blocks [0,308)) + per-wave poly prep (rest) ----
__global__ __launch_bounds__(256) void prep_pack(
    const float* __restrict__ geoms, const int* __restrict__ lengths,
    const float* __restrict__ w1, const float* __restrict__ b1,
    const float* __restrict__ w2,
    const int* __restrict__ roi_w, const int* __restrict__ roi_h,
    unsigned short* __restrict__ Wp, float* __restrict__ out)
{
    if (blockIdx.x < NPACK_BLK) {
        int i = blockIdx.x * 256 + threadIdx.x;
        if (i < WP_ELEMS) {
            int j    = i & 7;
            int lane = (i >> 3) & 63;
            int grp  = i >> 9;               // ks*14 + nt
            int nt   = grp % NTILES;
            int ks   = grp / NTILES;
            int k    = ks * 32 + (lane >> 4) * 8 + j;   // k = dk*112 + c
            int n    = nt * 16 + (lane & 15);
            float v = 0.f;
            if (k < 336) {
                int dk = k / C_MID, c = k - dk * C_MID;
                v = w2[(n * C_MID + c) * 3 + dk];
            }
            Wp[i] = f2bf(v);
        }
        return;
    }

    const int poly = (blockIdx.x - NPACK_BLK) * POLY_PER_BLK + (threadIdx.x >> 6);
    const int lane = threadIdx.x & 63;
    if (poly >= K_POLY) return;

    // ---- load polyline: one point per lane ----
    const float* gp = geoms + (size_t)poly * (PMAX * 2);
    float px = 0.f, py = 0.f;
    if (lane < PMAX) { float2 p = ((const float2*)gp)[lane]; px = p.x; py = p.y; }
    const int L = lengths[poly];

    // ---- per-lane segment length, shfl prefix-scan for cum ----
    float nx = __shfl(px, lane + 1);
    float ny = __shfl(py, lane + 1);
    float seg = 0.f;
    if (lane < L - 1 && lane < PMAX - 1) {
        float dx = nx - px, dy = ny - py;
        float sq = dx * dx + dy * dy;
        seg = (sq > 0.f) ? sqrtf(sq) : 0.f;
    }
    float incl = seg;
    #pragma unroll
    for (int d = 1; d < 32; d <<= 1) {
        float v = __shfl_up(incl, d, 32);
        if ((lane & 31) >= d) incl += v;
    }
    float cum = __shfl_up(incl, 1, 32);   // cum[i] = sum seg[0..i-1]
    if ((lane & 31) == 0) cum = 0.f;
    const float total = __shfl(incl, PMAX - 2);

    const float roiw = (float)roi_w[0], roih = (float)roi_h[0];
    const float halfx = roiw * 0.5f, halfy = roih * 0.5f;
    const bool degen = total < 1e-6f;
    const float x0g = __shfl(px, 0), y0g = __shfl(py, 0);

    // ---- resample 5 points, wave-uniform via ballot searchsorted ----
    float bxv[NUM_PTS], byv[NUM_PTS];
    #pragma unroll
    for (int j = 0; j < NUM_PTS; ++j) {
        float tj = total * (0.25f * (float)j);
        unsigned long long mlt = __ballot(lane < PMAX && cum < tj);
        int idx = (int)__popcll(mlt);     // first i with cum[i] >= tj
        idx = max(1, min(idx, L - 1));
        float c1 = __shfl(cum, idx - 1);
        float s1 = __shfl(seg, idx - 1);
        float ax = __shfl(px, idx - 1), ay = __shfl(py, idx - 1);
        float bx2 = __shfl(px, idx),    by2 = __shfl(py, idx);
        float tt = (tj - c1) / (s1 + 1e-8f);
        float fx = degen ? x0g : ax + tt * (bx2 - ax);
        float fy = degen ? y0g : ay + tt * (by2 - ay);
        bxv[j] = (fx + halfx) / roiw;
        byv[j] = (fy + halfy) / roih;
    }
    if (lane == 0) {
        float* co = out + (size_t)M_ROWS * GEO_DIM + (size_t)poly * (NUM_PTS * 2);
        #pragma unroll
        for (int j = 0; j < NUM_PTS; ++j) { co[2 * j] = bxv[j]; co[2 * j + 1] = byv[j]; }
    }

    // ---- A chunk: zero halo slots + K-pad, then conv1 (one channel/lane) ----
    unsigned short* chunk = (unsigned short*)out + (size_t)poly * CHUNK_STRIDE + CHUNK_OFF;
    unsigned int* cz = (unsigned int*)chunk;
    if (lane < 56) cz[lane] = 0u;          // slot 0 (elems 0..111)
    cz[336 + lane] = 0u;                   // elems 672..799 (slot 6 + K-pad)

    #pragma unroll
    for (int it = 0; it < 2; ++it) {
        int c = it * 64 + lane;
        if (c < C_MID) {
            const float* w = w1 + c * 6;
            float w0 = w[0], wa = w[1], wb = w[2], w3 = w[3], w4 = w[4], w5 = w[5];
            float bb = b1[c];
            #pragma unroll
            for (int p = 0; p < NUM_PTS; ++p) {
                float acc = bb + bxv[p] * wa + byv[p] * w4;
                if (p > 0)           acc += bxv[p - 1] * w0 + byv[p - 1] * w3;
                if (p < NUM_PTS - 1) acc += bxv[p + 1] * wb + byv[p + 1] * w5;
                chunk[(p + 1) * C_MID + c] = f2bf(fmaxf(acc, 0.f));
            }
        }
    }
}

// ---- kernel 2: all-B-in-LDS MFMA conv2, 12 waves/block (3/SIMD), 30-row units ----
__global__ __launch_bounds__(768, 3) void gemm2(
    const unsigned short* __restrict__ Wp,
    const float* __restrict__ b2, const float* __restrict__ gamma,
    const float* __restrict__ beta, float* __restrict__ out)
{
    __shared__ __align__(16) unsigned short s_B[WP_ELEMS];   // 157696 B

    const int t = threadIdx.x, lane = t & 63, wave = t >> 6;
    const int quad = lane >> 4, m = lane & 15;

    // ---- stage ALL of Wp into LDS (9856 x 16B chunks over 768 threads) ----
    #pragma unroll
    for (int it = 0; it < 13; ++it) {
        int idx = t + it * 768;
        if (idx < WP_ELEMS / 8)
            GLDS((const char*)Wp + (size_t)idx * 16, (char*)s_B + idx * 16);
    }
    __syncthreads();

    const unsigned short* A = (const unsigned short*)out;
    const float* cptr = out + (size_t)M_ROWS * GEO_DIM;
    const unsigned short* bl = s_B + lane * 8;   // per-lane B base; frag stride 512

    for (int u = blockIdx.x * WAVES2_B + wave; u < NUNITS; u += TOTW2) {
        const int rw = u * ROWS_W;

        // A frag bases (rows rw+m and rw+16+m; clamped rows' C output never stored)
        int r0 = min(rw + m, M_ROWS - 1);
        int r1 = min(rw + 16 + m, M_ROWS - 1);
        int poly0 = r0 / 5, p0 = r0 - poly0 * 5;
        int poly1 = r1 / 5, p1 = r1 - poly1 * 5;
        const unsigned short* Ab0 = A + (size_t)poly0 * CHUNK_STRIDE + CHUNK_OFF + p0 * C_MID + quad * 8;
        const unsigned short* Ab1 = A + (size_t)poly1 * CHUNK_STRIDE + CHUNK_OFF + p1 * C_MID + quad * 8;

        // coords for the unit's rows: one coalesced load (guarded at buffer end)
        int coff = rw * 2 + lane;
        float cv = (coff < 2 * M_ROWS) ? cptr[coff] : 0.f;

        f32x4 acc0[NTILES], acc1[NTILES];
        #pragma unroll
        for (int nt = 0; nt < NTILES; ++nt)
            #pragma unroll
            for (int i = 0; i < 4; ++i) { acc0[nt][i] = 0.f; acc1[nt][i] = 0.f; }

        #pragma unroll
        for (int ks = 0; ks < KSTEPS; ++ks) {
            short8 a0 = *(const short8*)(Ab0 + ks * 32);
            short8 a1 = *(const short8*)(Ab1 + ks * 32);
            const unsigned short* bp = bl + ks * (NTILES * 512);
            __builtin_amdgcn_s_setprio(1);
            #pragma unroll
            for (int nt = 0; nt < NTILES; ++nt) {
                short8 b = *(const short8*)(bp + nt * 512);
                acc0[nt] = __builtin_amdgcn_mfma_f32_16x16x32_bf16(a0, b, acc0[nt], 0, 0, 0);
                acc1[nt] = __builtin_amdgcn_mfma_f32_16x16x32_bf16(a1, b, acc1[nt], 0, 0, 0);
            }
            __builtin_amdgcn_s_setprio(0);
        }

        // ---- PE: cols 0..31 for rows rw..rw+29 (coords via shfl of cv) ----
        {
            const int col = lane & 31;
            const int d = col >> 4, isc = (col >> 3) & 1, fr = col & 7;
            const float pef = (float)(1 << fr) * 3.14159265358979323846f;
            #pragma unroll
            for (int it = 0; it < 15; ++it) {
                int j2 = it * 2 + (lane >> 5);          // row offset 0..29
                int r = rw + j2;
                float x = __shfl(cv, j2 * 2 + d);
                float arg = x * pef;
                if (r < M_ROWS)
                    out[(size_t)r * GEO_DIM + col] = isc ? __cosf(arg) : __sinf(arg);
            }
        }

        // ---- bias + ReLU + in-wave LayerNorm + store cols 32..255 ----
        unsigned lnoff = 0;
        asm volatile("" : "+v"(lnoff));   // opaque: prevent hoisting LN loads out of u-loop
        float bias[NTILES], gm[NTILES], bt[NTILES];
        #pragma unroll
        for (int nt = 0; nt < NTILES; ++nt) {
            unsigned col = lnoff + nt * 16 + m;
            bias[nt] = b2[col]; gm[nt] = gamma[col]; bt[nt] = beta[col];
        }

        #pragma unroll
        for (int g = 0; g < 2; ++g) {
            f32x4* acc = g ? acc1 : acc0;
            #pragma unroll
            for (int i = 0; i < 4; ++i) {
                float s = 0.f, q = 0.f;
                #pragma unroll
                for (int nt = 0; nt < NTILES; ++nt) {
                    float v = fmaxf(acc[nt][i] + bias[nt], 0.f);
                    acc[nt][i] = v;
                    s += v; q += v * v;
                }
                #pragma unroll
                for (int mk = 8; mk >= 1; mk >>= 1) {
                    s += __shfl_xor(s, mk, 64);
                    q += __shfl_xor(q, mk, 64);
                }
                float mu  = s * (1.f / C_OUT);
                float var = fmaxf(q * (1.f / C_OUT) - mu * mu, 0.f);
                float rs  = rsqrtf(var + 1e-5f);
                int r = rw + g * 16 + quad * 4 + i;
                // rows rw+30/31 (g==1, quad==3, i>=2) are the neighbor-poly garbage frag
                if (r < M_ROWS && !(g == 1 && quad == 3 && i >= 2)) {
                    size_t ob = (size_t)r * GEO_DIM + PE_DIM + m;
                    #pragma unroll
                    for (int nt = 0; nt < NTILES; ++nt)
                        out[ob + nt * 16] = (acc[nt][i] - mu) * rs * gm[nt] + bt[nt];
                }
            }
        }
    }
}

extern "C" void kernel_launch(void* const* d_in, const int* in_sizes, int n_in,
                              void* d_out, int out_size, void* d_ws, size_t ws_size,
                              hipStream_t stream) {
    const float* geoms   = (const float*)d_in[0];
    const int*   lengths = (const int*)d_in[1];
    const float* w1      = (const float*)d_in[2];
    const float* b1      = (const float*)d_in[3];
    const float* w2      = (const float*)d_in[4];
    const float* b2      = (const float*)d_in[5];
    const float* gamma   = (const float*)d_in[6];
    const float* beta    = (const float*)d_in[7];
    const int*   roi_w   = (const int*)d_in[8];
    const int*   roi_h   = (const int*)d_in[9];
    float* out = (float*)d_out;
    unsigned short* Wp = (unsigned short*)d_ws;   // 157696 B

    hipLaunchKernelGGL(prep_pack, dim3(NPACK_BLK + NPREP_BLK), dim3(256), 0, stream,
                       geoms, lengths, w1, b1, w2, roi_w, roi_h, Wp, out);
    hipLaunchKernelGGL(gemm2, dim3(NBLK2), dim3(768), 0, stream, Wp, b2, gamma, beta, out);
}

// Round 9
// 174.488 us; speedup vs baseline: 2.9294x; 1.2672x over previous
//
#include <hip/hip_runtime.h>
#include <math.h>

#define K_POLY   20000
#define PMAX     30
#define NUM_PTS  5
#define C_MID    112
#define C_OUT    224
#define PE_DIM   32
#define GEO_DIM  256
#define M_ROWS   (K_POLY*NUM_PTS)        // 100000

#define NTILES   14                      // 224/16 n-tiles
#define NT_H     7                       // n-tiles per wave (half)
#define KSTEPS   11                      // K padded 336 -> 352 = 11*32
#define WP_ELEMS (KSTEPS*NTILES*64*8)    // 78848 bf16 = 157696 B
#define NPACK_BLK ((WP_ELEMS+255)/256)   // 308
#define POLY_PER_BLK 4
#define NPREP_BLK ((K_POLY+POLY_PER_BLK-1)/POLY_PER_BLK)  // 5000

// in-place A storage: per-poly chunk of 7*112 bf16 (+16 pad) living in the
// cols-32..255 region of that poly's 5 output rows (overwritten later by LN)
#define CHUNK_STRIDE 2560    // ushort elems per poly block (5 rows * 256 * 2)
#define CHUNK_OFF    64      // ushort offset of chunk start (row 0, col 32)

#define ROWS_W   30                      // rows per pair-unit (6 whole polys)
#define NUNITS   ((M_ROWS+ROWS_W-1)/ROWS_W)     // 3334
#define WAVES2_B 12                      // 768-thread gemm2 blocks (3 waves/SIMD)
#define PAIRS_B  6                       // wave-pairs per block
#define NBLK2    256                     // 1 block/CU (LDS-bound)
#define NPAIRS   (NBLK2*PAIRS_B)         // 1536 pairs
#define NITER2   ((NUNITS+NPAIRS-1)/NPAIRS)     // 3 uniform iterations

typedef __attribute__((ext_vector_type(8))) short short8;
typedef __attribute__((ext_vector_type(4))) float f32x4;

__device__ inline unsigned short f2bf(float f) {
    union { float f; unsigned u; } v; v.f = f;
    return (unsigned short)((v.u + 0x7fffu + ((v.u >> 16) & 1u)) >> 16);
}

#define GLDS(gp, lp) __builtin_amdgcn_global_load_lds( \
    (const __attribute__((address_space(1))) void*)(gp), \
    (__attribute__((address_space(3))) void*)(lp), 16, 0, 0)

// ---- kernel 1: w2 pack (blocks [0,308)) + per-wave poly prep (rest) ----
__global__ __launch_bounds__(256) void prep_pack(
    const float* __restrict__ geoms, const int* __restrict__ lengths,
    const float* __restrict__ w1, const float* __restrict__ b1,
    const float* __restrict__ w2,
    const int* __restrict__ roi_w, const int* __restrict__ roi_h,
    unsigned short* __restrict__ Wp, float* __restrict__ out)
{
    if (blockIdx.x < NPACK_BLK) {
        int i = blockIdx.x * 256 + threadIdx.x;
        if (i < WP_ELEMS) {
            int j    = i & 7;
            int lane = (i >> 3) & 63;
            int grp  = i >> 9;               // ks*14 + nt
            int nt   = grp % NTILES;
            int ks   = grp / NTILES;
            int k    = ks * 32 + (lane >> 4) * 8 + j;   // k = dk*112 + c
            int n    = nt * 16 + (lane & 15);
            float v = 0.f;
            if (k < 336) {
                int dk = k / C_MID, c = k - dk * C_MID;
                v = w2[(n * C_MID + c) * 3 + dk];
            }
            Wp[i] = f2bf(v);
        }
        return;
    }

    const int poly = (blockIdx.x - NPACK_BLK) * POLY_PER_BLK + (threadIdx.x >> 6);
    const int lane = threadIdx.x & 63;
    if (poly >= K_POLY) return;

    // ---- load polyline: one point per lane ----
    const float* gp = geoms + (size_t)poly * (PMAX * 2);
    float px = 0.f, py = 0.f;
    if (lane < PMAX) { float2 p = ((const float2*)gp)[lane]; px = p.x; py = p.y; }
    const int L = lengths[poly];

    // ---- per-lane segment length, shfl prefix-scan for cum ----
    float nx = __shfl(px, lane + 1);
    float ny = __shfl(py, lane + 1);
    float seg = 0.f;
    if (lane < L - 1 && lane < PMAX - 1) {
        float dx = nx - px, dy = ny - py;
        float sq = dx * dx + dy * dy;
        seg = (sq > 0.f) ? sqrtf(sq) : 0.f;
    }
    float incl = seg;
    #pragma unroll
    for (int d = 1; d < 32; d <<= 1) {
        float v = __shfl_up(incl, d, 32);
        if ((lane & 31) >= d) incl += v;
    }
    float cum = __shfl_up(incl, 1, 32);   // cum[i] = sum seg[0..i-1]
    if ((lane & 31) == 0) cum = 0.f;
    const float total = __shfl(incl, PMAX - 2);

    const float roiw = (float)roi_w[0], roih = (float)roi_h[0];
    const float halfx = roiw * 0.5f, halfy = roih * 0.5f;
    const bool degen = total < 1e-6f;
    const float x0g = __shfl(px, 0), y0g = __shfl(py, 0);

    // ---- resample 5 points, wave-uniform via ballot searchsorted ----
    float bxv[NUM_PTS], byv[NUM_PTS];
    #pragma unroll
    for (int j = 0; j < NUM_PTS; ++j) {
        float tj = total * (0.25f * (float)j);
        unsigned long long mlt = __ballot(lane < PMAX && cum < tj);
        int idx = (int)__popcll(mlt);     // first i with cum[i] >= tj
        idx = max(1, min(idx, L - 1));
        float c1 = __shfl(cum, idx - 1);
        float s1 = __shfl(seg, idx - 1);
        float ax = __shfl(px, idx - 1), ay = __shfl(py, idx - 1);
        float bx2 = __shfl(px, idx),    by2 = __shfl(py, idx);
        float tt = (tj - c1) / (s1 + 1e-8f);
        float fx = degen ? x0g : ax + tt * (bx2 - ax);
        float fy = degen ? y0g : ay + tt * (by2 - ay);
        bxv[j] = (fx + halfx) / roiw;
        byv[j] = (fy + halfy) / roih;
    }
    if (lane == 0) {
        float* co = out + (size_t)M_ROWS * GEO_DIM + (size_t)poly * (NUM_PTS * 2);
        #pragma unroll
        for (int j = 0; j < NUM_PTS; ++j) { co[2 * j] = bxv[j]; co[2 * j + 1] = byv[j]; }
    }

    // ---- A chunk: zero halo slots + K-pad, then conv1 (one channel/lane) ----
    unsigned short* chunk = (unsigned short*)out + (size_t)poly * CHUNK_STRIDE + CHUNK_OFF;
    unsigned int* cz = (unsigned int*)chunk;
    if (lane < 56) cz[lane] = 0u;          // slot 0 (elems 0..111)
    cz[336 + lane] = 0u;                   // elems 672..799 (slot 6 + K-pad)

    #pragma unroll
    for (int it = 0; it < 2; ++it) {
        int c = it * 64 + lane;
        if (c < C_MID) {
            const float* w = w1 + c * 6;
            float w0 = w[0], wa = w[1], wb = w[2], w3 = w[3], w4 = w[4], w5 = w[5];
            float bb = b1[c];
            #pragma unroll
            for (int p = 0; p < NUM_PTS; ++p) {
                float acc = bb + bxv[p] * wa + byv[p] * w4;
                if (p > 0)           acc += bxv[p - 1] * w0 + byv[p - 1] * w3;
                if (p < NUM_PTS - 1) acc += bxv[p + 1] * wb + byv[p + 1] * w5;
                chunk[(p + 1) * C_MID + c] = f2bf(fmaxf(acc, 0.f));
            }
        }
    }
}

// ---- kernel 2: all-B-in-LDS MFMA conv2, wave-pair split-N (acc=56 regs/wave),
//      3 waves/SIMD, cross-wave LN via 3KB LDS ----
__global__ __launch_bounds__(768, 3) void gemm2(
    const unsigned short* __restrict__ Wp,
    const float* __restrict__ b2, const float* __restrict__ gamma,
    const float* __restrict__ beta, float* __restrict__ out)
{
    __shared__ __align__(16) unsigned short s_B[WP_ELEMS];   // 157696 B
    __shared__ float2 s_red[WAVES2_B][32];                   // 3072 B (total 160768)

    const int t = threadIdx.x, lane = t & 63, wave = t >> 6;
    const int quad = lane >> 4, m = lane & 15;
    const int half = wave & 1;           // n-half: cols [half*112, half*112+112)
    const int pairL = wave >> 1;         // 0..5

    // ---- stage ALL of Wp into LDS (9856 x 16B chunks over 768 threads) ----
    #pragma unroll
    for (int it = 0; it < 13; ++it) {
        int idx = t + it * 768;
        if (idx < WP_ELEMS / 8)
            GLDS((const char*)Wp + (size_t)idx * 16, (char*)s_B + idx * 16);
    }
    __syncthreads();

    const unsigned short* A = (const unsigned short*)out;
    const float* cptr = out + (size_t)M_ROWS * GEO_DIM;

    for (int iter = 0; iter < NITER2; ++iter) {
        const int u = blockIdx.x * PAIRS_B + pairL + iter * NPAIRS;
        const bool active = (u < NUNITS);
        const int rw = u * ROWS_W;

        f32x4 acc0[NT_H], acc1[NT_H];
        float prs[2][4], prq[2][4];
        float bias[NT_H], gm[NT_H], bt[NT_H];
        float cv = 0.f;

        if (active) {
            // A frag bases (rows rw+m, rw+16+m; clamped rows' stores are guarded)
            int r0 = min(rw + m, M_ROWS - 1);
            int r1 = min(rw + 16 + m, M_ROWS - 1);
            int poly0 = r0 / 5, p0 = r0 - poly0 * 5;
            int poly1 = r1 / 5, p1 = r1 - poly1 * 5;
            const unsigned short* Ab0 = A + (size_t)poly0 * CHUNK_STRIDE + CHUNK_OFF + p0 * C_MID + quad * 8;
            const unsigned short* Ab1 = A + (size_t)poly1 * CHUNK_STRIDE + CHUNK_OFF + p1 * C_MID + quad * 8;

            if (half == 0) {
                int coff = rw * 2 + lane;
                if (coff < 2 * M_ROWS) cv = cptr[coff];
            }

            #pragma unroll
            for (int nt = 0; nt < NT_H; ++nt)
                #pragma unroll
                for (int i = 0; i < 4; ++i) { acc0[nt][i] = 0.f; acc1[nt][i] = 0.f; }

            const unsigned short* bl = s_B + lane * 8 + (size_t)half * NT_H * 512;
            #pragma unroll
            for (int ks = 0; ks < KSTEPS; ++ks) {
                short8 a0 = *(const short8*)(Ab0 + ks * 32);
                short8 a1 = *(const short8*)(Ab1 + ks * 32);
                const unsigned short* bp = bl + ks * (NTILES * 512);
                __builtin_amdgcn_s_setprio(1);
                #pragma unroll
                for (int nt = 0; nt < NT_H; ++nt) {
                    short8 b = *(const short8*)(bp + nt * 512);
                    acc0[nt] = __builtin_amdgcn_mfma_f32_16x16x32_bf16(a0, b, acc0[nt], 0, 0, 0);
                    acc1[nt] = __builtin_amdgcn_mfma_f32_16x16x32_bf16(a1, b, acc1[nt], 0, 0, 0);
                }
                __builtin_amdgcn_s_setprio(0);
            }

            // bias + ReLU + per-half row partials -> s_red
            #pragma unroll
            for (int nt = 0; nt < NT_H; ++nt) {
                int col = half * 112 + nt * 16 + m;
                bias[nt] = b2[col]; gm[nt] = gamma[col]; bt[nt] = beta[col];
            }
            #pragma unroll
            for (int g = 0; g < 2; ++g) {
                f32x4* acc = g ? acc1 : acc0;
                #pragma unroll
                for (int i = 0; i < 4; ++i) {
                    float s = 0.f, q = 0.f;
                    #pragma unroll
                    for (int nt = 0; nt < NT_H; ++nt) {
                        float v = fmaxf(acc[nt][i] + bias[nt], 0.f);
                        acc[nt][i] = v;
                        s += v; q += v * v;
                    }
                    #pragma unroll
                    for (int mk = 8; mk >= 1; mk >>= 1) {
                        s += __shfl_xor(s, mk, 64);
                        q += __shfl_xor(q, mk, 64);
                    }
                    prs[g][i] = s; prq[g][i] = q;
                    if (m == 0) s_red[wave][g * 16 + quad * 4 + i] = make_float2(s, q);
                }
            }
        }
        __syncthreads();   // partials visible to partner wave

        if (active) {
            // ---- combine halves, LN + store cols for this half ----
            #pragma unroll
            for (int g = 0; g < 2; ++g) {
                f32x4* acc = g ? acc1 : acc0;
                #pragma unroll
                for (int i = 0; i < 4; ++i) {
                    float2 o = s_red[wave ^ 1][g * 16 + quad * 4 + i];
                    float stot = prs[g][i] + o.x;
                    float qtot = prq[g][i] + o.y;
                    float mu  = stot * (1.f / C_OUT);
                    float var = fmaxf(qtot * (1.f / C_OUT) - mu * mu, 0.f);
                    float rs  = rsqrtf(var + 1e-5f);
                    int r = rw + g * 16 + quad * 4 + i;
                    // rows rw+30/31 (g==1, quad==3, i>=2) are neighbor-poly garbage
                    if (r < M_ROWS && !(g == 1 && quad == 3 && i >= 2)) {
                        size_t ob = (size_t)r * GEO_DIM + PE_DIM + half * 112 + m;
                        #pragma unroll
                        for (int nt = 0; nt < NT_H; ++nt)
                            out[ob + nt * 16] = (acc[nt][i] - mu) * rs * gm[nt] + bt[nt];
                    }
                }
            }
            // ---- PE: cols 0..31 for rows rw..rw+29 (even wave of pair) ----
            if (half == 0) {
                const int col = lane & 31;
                const int d = col >> 4, isc = (col >> 3) & 1, fr = col & 7;
                const float pef = (float)(1 << fr) * 3.14159265358979323846f;
                #pragma unroll
                for (int it = 0; it < 15; ++it) {
                    int j2 = it * 2 + (lane >> 5);      // row offset 0..29
                    int r = rw + j2;
                    float x = __shfl(cv, j2 * 2 + d);
                    float arg = x * pef;
                    if (r < M_ROWS)
                        out[(size_t)r * GEO_DIM + col] = isc ? __cosf(arg) : __sinf(arg);
                }
            }
        }
        __syncthreads();   // protect s_red from next iteration's writes
    }
}

extern "C" void kernel_launch(void* const* d_in, const int* in_sizes, int n_in,
                              void* d_out, int out_size, void* d_ws, size_t ws_size,
                              hipStream_t stream) {
    const float* geoms   = (const float*)d_in[0];
    const int*   lengths = (const int*)d_in[1];
    const float* w1      = (const float*)d_in[2];
    const float* b1      = (const float*)d_in[3];
    const float* w2      = (const float*)d_in[4];
    const float* b2      = (const float*)d_in[5];
    const float* gamma   = (const float*)d_in[6];
    const float* beta    = (const float*)d_in[7];
    const int*   roi_w   = (const int*)d_in[8];
    const int*   roi_h   = (const int*)d_in[9];
    float* out = (float*)d_out;
    unsigned short* Wp = (unsigned short*)d_ws;   // 157696 B

    hipLaunchKernelGGL(prep_pack, dim3(NPACK_BLK + NPREP_BLK), dim3(256), 0, stream,
                       geoms, lengths, w1, b1, w2, roi_w, roi_h, Wp, out);
    hipLaunchKernelGGL(gemm2, dim3(NBLK2), dim3(768), 0, stream, Wp, b2, gamma, beta, out);
}